// Round 14
// baseline (81.567 us; speedup 1.0000x reference)
//
#include <hip/hip_runtime.h>

#define N_NODES 10000
#define N_EDGES 160000
#define IN_DIM 512
#define HID 128
#define OUT_DIM 64
#define CAP 64                      // ELL capacity; P(Poisson(16) > 64) ~ 3e-22

typedef __attribute__((ext_vector_type(8))) short bf16x8;
typedef __attribute__((ext_vector_type(4))) float f32x4;

// Native bf16 conversion (RNE)
__device__ inline ushort f2b(float f) {
    __bf16 h = (__bf16)f;
    return __builtin_bit_cast(ushort, h);
}
__device__ inline uint pack2(float a, float b) {
    return (uint)f2b(a) | ((uint)f2b(b) << 16);
}
__device__ inline float blo(uint u) { return __uint_as_float(u << 16); }
__device__ inline float bhi(uint u) { return __uint_as_float(u & 0xffff0000u); }

// ---------------------------------------------------------------------------
// prep: zero deg[] (int4) and convert W1/W2 -> bf16 (float4 chunks)
// ---------------------------------------------------------------------------
#define ZCH (N_NODES / 4)             // 2500 int4 chunks (deg)
#define W1CH (HID * IN_DIM / 4)       // 16384 float4 chunks per W1 matrix
#define W2CH (OUT_DIM * HID / 4)      // 2048 per W2 matrix
#define PREP_TOT (ZCH + 2 * W1CH + 2 * W2CH)

__global__ void prep(int* __restrict__ deg,
                     const float* __restrict__ w1l, const float* __restrict__ w1r,
                     const float* __restrict__ w2l, const float* __restrict__ w2r,
                     ushort* __restrict__ wc1, ushort* __restrict__ wc2) {
    int i = blockIdx.x * blockDim.x + threadIdx.x;
    if (i < ZCH) { ((int4*)deg)[i] = make_int4(0, 0, 0, 0); return; }
    i -= ZCH;
    const float* src; ushort* dst;
    if      (i < W1CH)            { src = w1l + (size_t)i * 4;             dst = wc1 + (size_t)i * 4; }
    else if (i < 2 * W1CH)        { int j = i - W1CH;          src = w1r + (size_t)j * 4; dst = wc1 + HID * IN_DIM + (size_t)j * 4; }
    else if (i < 2 * W1CH + W2CH) { int j = i - 2 * W1CH;      src = w2l + (size_t)j * 4; dst = wc2 + (size_t)j * 4; }
    else if (i < PREP_TOT - ZCH)  { int j = i - 2 * W1CH - W2CH; src = w2r + (size_t)j * 4; dst = wc2 + OUT_DIM * HID + (size_t)j * 4; }
    else return;
    float4 v = *reinterpret_cast<const float4*>(src);
    ushort4 o = make_ushort4(f2b(v.x), f2b(v.y), f2b(v.z), f2b(v.w));
    *reinterpret_cast<ushort4*>(dst) = o;
}

// ---------------------------------------------------------------------------
// MFMA GEMM body (R8-verified core)
// ---------------------------------------------------------------------------
template <typename AT, int BN, int K, int NT, int HALF>
__device__ __forceinline__ void gemm_body(int bx, int by,
    const AT* __restrict__ A, const ushort* __restrict__ B,
    ushort* __restrict__ C0, ushort* __restrict__ C1, int M) {
    constexpr int CF = BN / 32;
    __shared__ __align__(16) ushort Asm[32 * 64];
    __shared__ __align__(16) ushort Bsm[BN * 64];

    const int t    = threadIdx.x;
    const int lane = t & 63;
    const int w    = t >> 6;
    const int wr   = w & 1;
    const int wc   = w >> 1;
    const int m0   = by * 32;
    const int n0   = bx * BN;
    const int kch  = lane >> 4;
    const int lrow = lane & 15;

    f32x4 acc[CF] = {};

    for (int k0 = 0; k0 < K; k0 += 64) {
        {   // stage A (32 x 64) — one 16B chunk per thread
            int row = t >> 3, c = t & 7;
            int m = m0 + row;
            uint4 o = make_uint4(0u, 0u, 0u, 0u);
            if (m < M) {
                if constexpr (sizeof(AT) == 4) {
                    const float* p = (const float*)A + (size_t)m * K + k0 + c * 8;
                    float4 v0 = reinterpret_cast<const float4*>(p)[0];
                    float4 v1 = reinterpret_cast<const float4*>(p)[1];
                    o.x = pack2(v0.x, v0.y); o.y = pack2(v0.z, v0.w);
                    o.z = pack2(v1.x, v1.y); o.w = pack2(v1.z, v1.w);
                } else {
                    o = *reinterpret_cast<const uint4*>((const ushort*)A + (size_t)m * K + k0 + c * 8);
                }
            }
            *reinterpret_cast<uint4*>(&Asm[row * 64 + ((c ^ (row & 7)) << 3)]) = o;
        }
        #pragma unroll
        for (int ch = t; ch < BN * 8; ch += 256) {   // stage B (BN x 64), bf16
            int row = ch >> 3, c = ch & 7;
            uint4 o = *reinterpret_cast<const uint4*>(&B[(size_t)(n0 + row) * K + k0 + c * 8]);
            *reinterpret_cast<uint4*>(&Bsm[row * 64 + ((c ^ (row & 7)) << 3)]) = o;
        }
        __syncthreads();

        const int arow = wr * 16 + lrow;
        #pragma unroll
        for (int h = 0; h < 2; ++h) {
            int c = h * 4 + kch;
            bf16x8 afr = *reinterpret_cast<const bf16x8*>(&Asm[arow * 64 + ((c ^ (arow & 7)) << 3)]);
            #pragma unroll
            for (int cf = 0; cf < CF; ++cf) {
                int brow = wc * (BN / 2) + cf * 16 + lrow;
                bf16x8 bfr = *reinterpret_cast<const bf16x8*>(&Bsm[brow * 64 + ((c ^ (brow & 7)) << 3)]);
                acc[cf] = __builtin_amdgcn_mfma_f32_16x16x32_bf16(afr, bfr, acc[cf], 0, 0, 0);
            }
        }
        __syncthreads();
    }

    #pragma unroll
    for (int cf = 0; cf < CF; ++cf) {
        int col = n0 + wc * (BN / 2) + cf * 16 + lrow;
        #pragma unroll
        for (int j = 0; j < 4; ++j) {
            int row = m0 + wr * 16 + kch * 4 + j;
            if (row >= M) continue;
            if (col < HALF) C0[(size_t)row * HALF + col] = f2b(acc[cf][j]);
            else            C1[(size_t)row * (NT - HALF) + (col - HALF)] = f2b(acc[cf][j]);
        }
    }
}

// ---------------------------------------------------------------------------
#define ROWB ((N_NODES + 31) / 32)          // 313
#define G1_BLOCKS (2 * ROWB)                // 626 (NT=256 / BN=128)
#define FILL_BLOCKS ((N_EDGES + 255) / 256) // 625

__global__ __launch_bounds__(256) void fat_gemm1_fill(
    const float* __restrict__ x, const ushort* __restrict__ wc1,
    ushort* __restrict__ XL, ushort* __restrict__ XR,
    const int* __restrict__ src, const int* __restrict__ dst,
    int* __restrict__ deg, int* __restrict__ bell) {
    int b = blockIdx.x;
    if (b < G1_BLOCKS) {
        gemm_body<float, 128, IN_DIM, 256, HID>(b / ROWB, b % ROWB, x, wc1, XL, XR, N_NODES);
    } else {
        int e = (b - G1_BLOCKS) * 256 + threadIdx.x;
        if (e < N_EDGES) {
            int d = dst[e];
            int pos = atomicAdd(&deg[d], 1);
            if (pos < CAP) bell[d * CAP + pos] = src[e];
        }
    }
}

__global__ __launch_bounds__(256) void gemm2_kernel(
    const ushort* __restrict__ hb, const ushort* __restrict__ wc2,
    ushort* __restrict__ HL, ushort* __restrict__ HR) {
    gemm_body<ushort, 64, HID, 128, OUT_DIM>(blockIdx.x / ROWB, blockIdx.x % ROWB,
                                             hb, wc2, HL, HR, N_NODES);
}

// ---------------------------------------------------------------------------
__global__ __launch_bounds__(256) void gather1(
    const ushort* __restrict__ V, const ushort* __restrict__ xr,
    const float* __restrict__ b, const int* __restrict__ deg,
    const int* __restrict__ bell, ushort* __restrict__ out) {
    int wave = threadIdx.x >> 6;
    int lane = threadIdx.x & 63;
    int n = blockIdx.x * 4 + wave;
    if (n >= N_NODES) return;

    int d = min(deg[n], CAP);
    const int* lst = bell + (size_t)n * CAP;

    float a0 = 0.f, a1 = 0.f;
    int i = 0;
    for (; i + 4 <= d; i += 4) {
        int s0 = lst[i], s1 = lst[i + 1], s2 = lst[i + 2], s3 = lst[i + 3];
        uint u0 = *(const uint*)(V + (size_t)s0 * 128 + lane * 2);
        uint u1 = *(const uint*)(V + (size_t)s1 * 128 + lane * 2);
        uint u2 = *(const uint*)(V + (size_t)s2 * 128 + lane * 2);
        uint u3 = *(const uint*)(V + (size_t)s3 * 128 + lane * 2);
        a0 += blo(u0) + blo(u1) + blo(u2) + blo(u3);
        a1 += bhi(u0) + bhi(u1) + bhi(u2) + bhi(u3);
    }
    for (; i < d; ++i) {
        uint u = *(const uint*)(V + (size_t)lst[i] * 128 + lane * 2);
        a0 += blo(u); a1 += bhi(u);
    }

    float inv = (d > 0) ? (1.0f / (float)d) : 0.0f;
    uint ux = *(const uint*)(xr + (size_t)n * 128 + lane * 2);
    float v0 = fmaxf(a0 * inv + blo(ux) + b[lane * 2], 0.f);
    float v1 = fmaxf(a1 * inv + bhi(ux) + b[lane * 2 + 1], 0.f);
    *(uint*)(out + (size_t)n * 128 + lane * 2) = pack2(v0, v1);
}

__global__ __launch_bounds__(256) void gather2(
    const ushort* __restrict__ V, const ushort* __restrict__ xr,
    const float* __restrict__ b, const int* __restrict__ deg,
    const int* __restrict__ bell, float* __restrict__ out) {
    int wave = threadIdx.x >> 6;
    int lane = threadIdx.x & 63;
    int n = blockIdx.x * 4 + wave;
    if (n >= N_NODES) return;

    int d = min(deg[n], CAP);
    const int* lst = bell + (size_t)n * CAP;

    float a0 = 0.f;
    int i = 0;
    for (; i + 4 <= d; i += 4) {
        int s0 = lst[i], s1 = lst[i + 1], s2 = lst[i + 2], s3 = lst[i + 3];
        a0 += blo((uint)V[(size_t)s0 * 64 + lane]) + blo((uint)V[(size_t)s1 * 64 + lane])
            + blo((uint)V[(size_t)s2 * 64 + lane]) + blo((uint)V[(size_t)s3 * 64 + lane]);
    }
    for (; i < d; ++i) a0 += blo((uint)V[(size_t)lst[i] * 64 + lane]);

    float inv = (d > 0) ? (1.0f / (float)d) : 0.0f;
    out[(size_t)n * 64 + lane] = a0 * inv + blo((uint)xr[(size_t)n * 64 + lane]) + b[lane];
}

// ---------------------------------------------------------------------------
// MEASUREMENT ROUND: prep/gather1/gemm2/gather2 each launched TWICE
// (idempotent — identical inputs/outputs). dur delta vs R13 isolates
// t(prep)+t(gather1)+t(gemm2)+t(gather2) + 4x dispatch overhead.
// ---------------------------------------------------------------------------
extern "C" void kernel_launch(void* const* d_in, const int* in_sizes, int n_in,
                              void* d_out, int out_size, void* d_ws, size_t ws_size,
                              hipStream_t stream) {
    const float* x   = (const float*)d_in[0];
    const int*   ei  = (const int*)d_in[1];
    const int*   src = ei;
    const int*   dst = ei + N_EDGES;
    const float* W1l = (const float*)d_in[2];
    const float* W1r = (const float*)d_in[3];
    const float* b1  = (const float*)d_in[4];
    const float* W2l = (const float*)d_in[5];
    const float* W2r = (const float*)d_in[6];
    const float* b2  = (const float*)d_in[7];
    float*       out = (float*)d_out;

    int* deg  = (int*)d_ws;                                 // N
    int* bell = deg + N_NODES;                              // N*CAP
    ushort* wc1 = (ushort*)(bell + (size_t)N_NODES * CAP);  // 2*128*512 bf16
    ushort* wc2 = wc1 + (size_t)2 * HID * IN_DIM;           // 2*64*128 bf16
    ushort* XL  = wc2 + (size_t)2 * OUT_DIM * HID;          // N*128 bf16
    ushort* XR  = XL + (size_t)N_NODES * HID;               // N*128 bf16
    ushort* hb  = XR + (size_t)N_NODES * HID;               // N*128 bf16
    ushort* HL  = hb + (size_t)N_NODES * HID;               // N*64 bf16
    ushort* HR  = HL + (size_t)N_NODES * OUT_DIM;           // N*64 bf16

    prep<<<(PREP_TOT + 255) / 256, 256, 0, stream>>>(deg, W1l, W1r, W2l, W2r, wc1, wc2);
    prep<<<(PREP_TOT + 255) / 256, 256, 0, stream>>>(deg, W1l, W1r, W2l, W2r, wc1, wc2);

    fat_gemm1_fill<<<G1_BLOCKS + FILL_BLOCKS, 256, 0, stream>>>(
        x, wc1, XL, XR, src, dst, deg, bell);

    gather1<<<(N_NODES + 3) / 4, 256, 0, stream>>>(XL, XR, b1, deg, bell, hb);
    gather1<<<(N_NODES + 3) / 4, 256, 0, stream>>>(XL, XR, b1, deg, bell, hb);

    gemm2_kernel<<<2 * ROWB, 256, 0, stream>>>(hb, wc2, HL, HR);
    gemm2_kernel<<<2 * ROWB, 256, 0, stream>>>(hb, wc2, HL, HR);

    gather2<<<(N_NODES + 3) / 4, 256, 0, stream>>>(HL, HR, b2, deg, bell, out);
    gather2<<<(N_NODES + 3) / 4, 256, 0, stream>>>(HL, HR, b2, deg, bell, out);
}

// Round 15
// 72.330 us; speedup vs baseline: 1.1277x; 1.1277x over previous
//
#include <hip/hip_runtime.h>

#define N_NODES 10000
#define N_EDGES 160000
#define IN_DIM 512
#define HID 128
#define OUT_DIM 64
#define CAP 64                      // ELL capacity; P(Poisson(16) > 64) ~ 3e-22

typedef __attribute__((ext_vector_type(8))) short bf16x8;
typedef __attribute__((ext_vector_type(4))) float f32x4;

// Native bf16 conversion (RNE)
__device__ inline ushort f2b(float f) {
    __bf16 h = (__bf16)f;
    return __builtin_bit_cast(ushort, h);
}
__device__ inline uint pack2(float a, float b) {
    return (uint)f2b(a) | ((uint)f2b(b) << 16);
}
__device__ inline float blo(uint u) { return __uint_as_float(u << 16); }
__device__ inline float bhi(uint u) { return __uint_as_float(u & 0xffff0000u); }

// ---------------------------------------------------------------------------
// prep: zero deg[] (int4) and convert W1/W2 -> bf16 (float4 chunks)
// ---------------------------------------------------------------------------
#define ZCH (N_NODES / 4)             // 2500 int4 chunks (deg)
#define W1CH (HID * IN_DIM / 4)       // 16384 float4 chunks per W1 matrix
#define W2CH (OUT_DIM * HID / 4)      // 2048 per W2 matrix
#define PREP_TOT (ZCH + 2 * W1CH + 2 * W2CH)

__global__ void prep(int* __restrict__ deg,
                     const float* __restrict__ w1l, const float* __restrict__ w1r,
                     const float* __restrict__ w2l, const float* __restrict__ w2r,
                     ushort* __restrict__ wc1, ushort* __restrict__ wc2) {
    int i = blockIdx.x * blockDim.x + threadIdx.x;
    if (i < ZCH) { ((int4*)deg)[i] = make_int4(0, 0, 0, 0); return; }
    i -= ZCH;
    const float* src; ushort* dst;
    if      (i < W1CH)            { src = w1l + (size_t)i * 4;             dst = wc1 + (size_t)i * 4; }
    else if (i < 2 * W1CH)        { int j = i - W1CH;          src = w1r + (size_t)j * 4; dst = wc1 + HID * IN_DIM + (size_t)j * 4; }
    else if (i < 2 * W1CH + W2CH) { int j = i - 2 * W1CH;      src = w2l + (size_t)j * 4; dst = wc2 + (size_t)j * 4; }
    else if (i < PREP_TOT - ZCH)  { int j = i - 2 * W1CH - W2CH; src = w2r + (size_t)j * 4; dst = wc2 + OUT_DIM * HID + (size_t)j * 4; }
    else return;
    float4 v = *reinterpret_cast<const float4*>(src);
    ushort4 o = make_ushort4(f2b(v.x), f2b(v.y), f2b(v.z), f2b(v.w));
    *reinterpret_cast<ushort4*>(dst) = o;
}

// ---------------------------------------------------------------------------
// MFMA GEMM body (R8-verified core, BK now templated; BK=128 halves barriers).
// BM=32. 4 waves: wave w -> rows (w&1)*16, cols (w>>1)*(BN/2), CF=BN/32.
// XOR swizzle chunk' = chunk^(row&7), bijective for RCH in {8,16};
// frag reads stay 2-way bank aliased (free). Outputs bf16 split at HALF.
// ---------------------------------------------------------------------------
template <typename AT, int BN, int BK, int K, int NT, int HALF>
__device__ __forceinline__ void gemm_body(int bx, int by,
    const AT* __restrict__ A, const ushort* __restrict__ B,
    ushort* __restrict__ C0, ushort* __restrict__ C1, int M) {
    constexpr int CF  = BN / 32;
    constexpr int RCH = BK / 8;              // 16B chunks per LDS row
    __shared__ __align__(16) ushort Asm[32 * BK];
    __shared__ __align__(16) ushort Bsm[BN * BK];

    const int t    = threadIdx.x;
    const int lane = t & 63;
    const int w    = t >> 6;
    const int wr   = w & 1;
    const int wc   = w >> 1;
    const int m0   = by * 32;
    const int n0   = bx * BN;
    const int kch  = lane >> 4;
    const int lrow = lane & 15;

    f32x4 acc[CF] = {};

    for (int k0 = 0; k0 < K; k0 += BK) {
        // stage A (32 x BK)
        #pragma unroll
        for (int l = t; l < 32 * RCH; l += 256) {
            int row = l / RCH, c = l % RCH;
            int m = m0 + row;
            uint4 o = make_uint4(0u, 0u, 0u, 0u);
            if (m < M) {
                if constexpr (sizeof(AT) == 4) {
                    const float* p = (const float*)A + (size_t)m * K + k0 + c * 8;
                    float4 v0 = reinterpret_cast<const float4*>(p)[0];
                    float4 v1 = reinterpret_cast<const float4*>(p)[1];
                    o.x = pack2(v0.x, v0.y); o.y = pack2(v0.z, v0.w);
                    o.z = pack2(v1.x, v1.y); o.w = pack2(v1.z, v1.w);
                } else {
                    o = *reinterpret_cast<const uint4*>((const ushort*)A + (size_t)m * K + k0 + c * 8);
                }
            }
            *reinterpret_cast<uint4*>(&Asm[row * BK + ((c ^ (row & 7)) << 3)]) = o;
        }
        // stage B (BN x BK), bf16 source
        #pragma unroll
        for (int l = t; l < BN * RCH; l += 256) {
            int row = l / RCH, c = l % RCH;
            uint4 o = *reinterpret_cast<const uint4*>(&B[(size_t)(n0 + row) * K + k0 + c * 8]);
            *reinterpret_cast<uint4*>(&Bsm[row * BK + ((c ^ (row & 7)) << 3)]) = o;
        }
        __syncthreads();

        const int arow = wr * 16 + lrow;
        #pragma unroll
        for (int ks = 0; ks < BK / 32; ++ks) {
            int c = ks * 4 + kch;
            bf16x8 afr = *reinterpret_cast<const bf16x8*>(&Asm[arow * BK + ((c ^ (arow & 7)) << 3)]);
            #pragma unroll
            for (int cf = 0; cf < CF; ++cf) {
                int brow = wc * (BN / 2) + cf * 16 + lrow;
                bf16x8 bfr = *reinterpret_cast<const bf16x8*>(&Bsm[brow * BK + ((c ^ (brow & 7)) << 3)]);
                acc[cf] = __builtin_amdgcn_mfma_f32_16x16x32_bf16(afr, bfr, acc[cf], 0, 0, 0);
            }
        }
        __syncthreads();
    }

    // epilogue: col = lane&15 (+frag*16), row = (lane>>4)*4 + j  [m89 layout]
    #pragma unroll
    for (int cf = 0; cf < CF; ++cf) {
        int col = n0 + wc * (BN / 2) + cf * 16 + lrow;
        #pragma unroll
        for (int j = 0; j < 4; ++j) {
            int row = m0 + wr * 16 + kch * 4 + j;
            if (row >= M) continue;
            if (col < HALF) C0[(size_t)row * HALF + col] = f2b(acc[cf][j]);
            else            C1[(size_t)row * (NT - HALF) + (col - HALF)] = f2b(acc[cf][j]);
        }
    }
}

// ---------------------------------------------------------------------------
#define ROWB ((N_NODES + 31) / 32)          // 313
#define G1_BLOCKS (2 * ROWB)                // 626 (NT=256 / BN=128)
#define FILL_BLOCKS ((N_EDGES + 255) / 256) // 625

__global__ __launch_bounds__(256) void fat_gemm1_fill(
    const float* __restrict__ x, const ushort* __restrict__ wc1,
    ushort* __restrict__ XL, ushort* __restrict__ XR,
    const int* __restrict__ src, const int* __restrict__ dst,
    int* __restrict__ deg, int* __restrict__ bell) {
    int b = blockIdx.x;
    if (b < G1_BLOCKS) {
        gemm_body<float, 128, 128, IN_DIM, 256, HID>(b / ROWB, b % ROWB, x, wc1, XL, XR, N_NODES);
    } else {
        int e = (b - G1_BLOCKS) * 256 + threadIdx.x;
        if (e < N_EDGES) {
            int d = dst[e];
            int pos = atomicAdd(&deg[d], 1);
            if (pos < CAP) bell[d * CAP + pos] = src[e];
        }
    }
}

// Pure layer-1 GEMM (identical outputs — duplicate for timing decomposition)
__global__ __launch_bounds__(256) void gemm1_only(
    const float* __restrict__ x, const ushort* __restrict__ wc1,
    ushort* __restrict__ XL, ushort* __restrict__ XR) {
    gemm_body<float, 128, 128, IN_DIM, 256, HID>(blockIdx.x / ROWB, blockIdx.x % ROWB,
                                                 x, wc1, XL, XR, N_NODES);
}

// Layer-2 GEMM: K=BK=128 -> single staging iteration
__global__ __launch_bounds__(256) void gemm2_kernel(
    const ushort* __restrict__ hb, const ushort* __restrict__ wc2,
    ushort* __restrict__ HL, ushort* __restrict__ HR) {
    gemm_body<ushort, 64, 128, HID, 128, OUT_DIM>(blockIdx.x / ROWB, blockIdx.x % ROWB,
                                                  hb, wc2, HL, HR, N_NODES);
}

// ---------------------------------------------------------------------------
__global__ __launch_bounds__(256) void gather1(
    const ushort* __restrict__ V, const ushort* __restrict__ xr,
    const float* __restrict__ b, const int* __restrict__ deg,
    const int* __restrict__ bell, ushort* __restrict__ out) {
    int wave = threadIdx.x >> 6;
    int lane = threadIdx.x & 63;
    int n = blockIdx.x * 4 + wave;
    if (n >= N_NODES) return;

    int d = min(deg[n], CAP);
    const int* lst = bell + (size_t)n * CAP;

    float a0 = 0.f, a1 = 0.f;
    int i = 0;
    for (; i + 4 <= d; i += 4) {
        int s0 = lst[i], s1 = lst[i + 1], s2 = lst[i + 2], s3 = lst[i + 3];
        uint u0 = *(const uint*)(V + (size_t)s0 * 128 + lane * 2);
        uint u1 = *(const uint*)(V + (size_t)s1 * 128 + lane * 2);
        uint u2 = *(const uint*)(V + (size_t)s2 * 128 + lane * 2);
        uint u3 = *(const uint*)(V + (size_t)s3 * 128 + lane * 2);
        a0 += blo(u0) + blo(u1) + blo(u2) + blo(u3);
        a1 += bhi(u0) + bhi(u1) + bhi(u2) + bhi(u3);
    }
    for (; i < d; ++i) {
        uint u = *(const uint*)(V + (size_t)lst[i] * 128 + lane * 2);
        a0 += blo(u); a1 += bhi(u);
    }

    float inv = (d > 0) ? (1.0f / (float)d) : 0.0f;
    uint ux = *(const uint*)(xr + (size_t)n * 128 + lane * 2);
    float v0 = fmaxf(a0 * inv + blo(ux) + b[lane * 2], 0.f);
    float v1 = fmaxf(a1 * inv + bhi(ux) + b[lane * 2 + 1], 0.f);
    *(uint*)(out + (size_t)n * 128 + lane * 2) = pack2(v0, v1);
}

__global__ __launch_bounds__(256) void gather2(
    const ushort* __restrict__ V, const ushort* __restrict__ xr,
    const float* __restrict__ b, const int* __restrict__ deg,
    const int* __restrict__ bell, float* __restrict__ out) {
    int wave = threadIdx.x >> 6;
    int lane = threadIdx.x & 63;
    int n = blockIdx.x * 4 + wave;
    if (n >= N_NODES) return;

    int d = min(deg[n], CAP);
    const int* lst = bell + (size_t)n * CAP;

    float a0 = 0.f;
    int i = 0;
    for (; i + 4 <= d; i += 4) {
        int s0 = lst[i], s1 = lst[i + 1], s2 = lst[i + 2], s3 = lst[i + 3];
        a0 += blo((uint)V[(size_t)s0 * 64 + lane]) + blo((uint)V[(size_t)s1 * 64 + lane])
            + blo((uint)V[(size_t)s2 * 64 + lane]) + blo((uint)V[(size_t)s3 * 64 + lane]);
    }
    for (; i < d; ++i) a0 += blo((uint)V[(size_t)lst[i] * 64 + lane]);

    float inv = (d > 0) ? (1.0f / (float)d) : 0.0f;
    out[(size_t)n * 64 + lane] = a0 * inv + blo((uint)xr[(size_t)n * 64 + lane]) + b[lane];
}

// ---------------------------------------------------------------------------
// R15: BK=128 everywhere + one duplicated PURE gemm1 (timing probe).
// ---------------------------------------------------------------------------
extern "C" void kernel_launch(void* const* d_in, const int* in_sizes, int n_in,
                              void* d_out, int out_size, void* d_ws, size_t ws_size,
                              hipStream_t stream) {
    const float* x   = (const float*)d_in[0];
    const int*   ei  = (const int*)d_in[1];
    const int*   src = ei;
    const int*   dst = ei + N_EDGES;
    const float* W1l = (const float*)d_in[2];
    const float* W1r = (const float*)d_in[3];
    const float* b1  = (const float*)d_in[4];
    const float* W2l = (const float*)d_in[5];
    const float* W2r = (const float*)d_in[6];
    const float* b2  = (const float*)d_in[7];
    float*       out = (float*)d_out;

    int* deg  = (int*)d_ws;                                 // N
    int* bell = deg + N_NODES;                              // N*CAP
    ushort* wc1 = (ushort*)(bell + (size_t)N_NODES * CAP);  // 2*128*512 bf16
    ushort* wc2 = wc1 + (size_t)2 * HID * IN_DIM;           // 2*64*128 bf16
    ushort* XL  = wc2 + (size_t)2 * OUT_DIM * HID;          // N*128 bf16
    ushort* XR  = XL + (size_t)N_NODES * HID;               // N*128 bf16
    ushort* hb  = XR + (size_t)N_NODES * HID;               // N*128 bf16
    ushort* HL  = hb + (size_t)N_NODES * HID;               // N*64 bf16
    ushort* HR  = HL + (size_t)N_NODES * OUT_DIM;           // N*64 bf16

    prep<<<(PREP_TOT + 255) / 256, 256, 0, stream>>>(deg, W1l, W1r, W2l, W2r, wc1, wc2);

    fat_gemm1_fill<<<G1_BLOCKS + FILL_BLOCKS, 256, 0, stream>>>(
        x, wc1, XL, XR, src, dst, deg, bell);

    // timing probe: pure gemm1, rewrites identical XL/XR (idempotent)
    gemm1_only<<<G1_BLOCKS, 256, 0, stream>>>(x, wc1, XL, XR);

    gather1<<<(N_NODES + 3) / 4, 256, 0, stream>>>(XL, XR, b1, deg, bell, hb);

    gemm2_kernel<<<2 * ROWB, 256, 0, stream>>>(hb, wc2, HL, HR);

    gather2<<<(N_NODES + 3) / 4, 256, 0, stream>>>(HL, HR, b2, deg, bell, out);
}

// Round 16
// 64.467 us; speedup vs baseline: 1.2653x; 1.1220x over previous
//
#include <hip/hip_runtime.h>

#define N_NODES 10000
#define N_EDGES 160000
#define IN_DIM 512
#define HID 128
#define OUT_DIM 64
#define CAP 64                      // ELL capacity; P(Poisson(16) > 64) ~ 3e-22

typedef __attribute__((ext_vector_type(8))) short bf16x8;
typedef __attribute__((ext_vector_type(4))) float f32x4;

// Native bf16 conversion (RNE)
__device__ inline ushort f2b(float f) {
    __bf16 h = (__bf16)f;
    return __builtin_bit_cast(ushort, h);
}
__device__ inline uint pack2(float a, float b) {
    return (uint)f2b(a) | ((uint)f2b(b) << 16);
}
__device__ inline float blo(uint u) { return __uint_as_float(u << 16); }
__device__ inline float bhi(uint u) { return __uint_as_float(u & 0xffff0000u); }

// ---------------------------------------------------------------------------
// prep: zero deg[] (int4) and convert W1/W2 -> bf16 (float4 chunks)
// ---------------------------------------------------------------------------
#define ZCH (N_NODES / 4)             // 2500 int4 chunks (deg)
#define W1CH (HID * IN_DIM / 4)       // 16384 float4 chunks per W1 matrix
#define W2CH (OUT_DIM * HID / 4)      // 2048 per W2 matrix
#define PREP_TOT (ZCH + 2 * W1CH + 2 * W2CH)

__global__ void prep(int* __restrict__ deg,
                     const float* __restrict__ w1l, const float* __restrict__ w1r,
                     const float* __restrict__ w2l, const float* __restrict__ w2r,
                     ushort* __restrict__ wc1, ushort* __restrict__ wc2) {
    int i = blockIdx.x * blockDim.x + threadIdx.x;
    if (i < ZCH) { ((int4*)deg)[i] = make_int4(0, 0, 0, 0); return; }
    i -= ZCH;
    const float* src; ushort* dst;
    if      (i < W1CH)            { src = w1l + (size_t)i * 4;             dst = wc1 + (size_t)i * 4; }
    else if (i < 2 * W1CH)        { int j = i - W1CH;          src = w1r + (size_t)j * 4; dst = wc1 + HID * IN_DIM + (size_t)j * 4; }
    else if (i < 2 * W1CH + W2CH) { int j = i - 2 * W1CH;      src = w2l + (size_t)j * 4; dst = wc2 + (size_t)j * 4; }
    else if (i < PREP_TOT - ZCH)  { int j = i - 2 * W1CH - W2CH; src = w2r + (size_t)j * 4; dst = wc2 + OUT_DIM * HID + (size_t)j * 4; }
    else return;
    float4 v = *reinterpret_cast<const float4*>(src);
    ushort4 o = make_ushort4(f2b(v.x), f2b(v.y), f2b(v.z), f2b(v.w));
    *reinterpret_cast<ushort4*>(dst) = o;
}

// ---------------------------------------------------------------------------
// MFMA GEMM body (R8-verified core, BK templated; BK=128 verified R15).
// ---------------------------------------------------------------------------
template <typename AT, int BN, int BK, int K, int NT, int HALF>
__device__ __forceinline__ void gemm_body(int bx, int by,
    const AT* __restrict__ A, const ushort* __restrict__ B,
    ushort* __restrict__ C0, ushort* __restrict__ C1, int M) {
    constexpr int CF  = BN / 32;
    constexpr int RCH = BK / 8;              // 16B chunks per LDS row
    __shared__ __align__(16) ushort Asm[32 * BK];
    __shared__ __align__(16) ushort Bsm[BN * BK];

    const int t    = threadIdx.x;
    const int lane = t & 63;
    const int w    = t >> 6;
    const int wr   = w & 1;
    const int wc   = w >> 1;
    const int m0   = by * 32;
    const int n0   = bx * BN;
    const int kch  = lane >> 4;
    const int lrow = lane & 15;

    f32x4 acc[CF] = {};

    for (int k0 = 0; k0 < K; k0 += BK) {
        // stage A (32 x BK)
        #pragma unroll
        for (int l = t; l < 32 * RCH; l += 256) {
            int row = l / RCH, c = l % RCH;
            int m = m0 + row;
            uint4 o = make_uint4(0u, 0u, 0u, 0u);
            if (m < M) {
                if constexpr (sizeof(AT) == 4) {
                    const float* p = (const float*)A + (size_t)m * K + k0 + c * 8;
                    float4 v0 = reinterpret_cast<const float4*>(p)[0];
                    float4 v1 = reinterpret_cast<const float4*>(p)[1];
                    o.x = pack2(v0.x, v0.y); o.y = pack2(v0.z, v0.w);
                    o.z = pack2(v1.x, v1.y); o.w = pack2(v1.z, v1.w);
                } else {
                    o = *reinterpret_cast<const uint4*>((const ushort*)A + (size_t)m * K + k0 + c * 8);
                }
            }
            *reinterpret_cast<uint4*>(&Asm[row * BK + ((c ^ (row & 7)) << 3)]) = o;
        }
        // stage B (BN x BK), bf16 source
        #pragma unroll
        for (int l = t; l < BN * RCH; l += 256) {
            int row = l / RCH, c = l % RCH;
            uint4 o = *reinterpret_cast<const uint4*>(&B[(size_t)(n0 + row) * K + k0 + c * 8]);
            *reinterpret_cast<uint4*>(&Bsm[row * BK + ((c ^ (row & 7)) << 3)]) = o;
        }
        __syncthreads();

        const int arow = wr * 16 + lrow;
        #pragma unroll
        for (int ks = 0; ks < BK / 32; ++ks) {
            int c = ks * 4 + kch;
            bf16x8 afr = *reinterpret_cast<const bf16x8*>(&Asm[arow * BK + ((c ^ (arow & 7)) << 3)]);
            #pragma unroll
            for (int cf = 0; cf < CF; ++cf) {
                int brow = wc * (BN / 2) + cf * 16 + lrow;
                bf16x8 bfr = *reinterpret_cast<const bf16x8*>(&Bsm[brow * BK + ((c ^ (brow & 7)) << 3)]);
                acc[cf] = __builtin_amdgcn_mfma_f32_16x16x32_bf16(afr, bfr, acc[cf], 0, 0, 0);
            }
        }
        __syncthreads();
    }

    // epilogue: col = lane&15 (+frag*16), row = (lane>>4)*4 + j  [m89 layout]
    #pragma unroll
    for (int cf = 0; cf < CF; ++cf) {
        int col = n0 + wc * (BN / 2) + cf * 16 + lrow;
        #pragma unroll
        for (int j = 0; j < 4; ++j) {
            int row = m0 + wr * 16 + kch * 4 + j;
            if (row >= M) continue;
            if (col < HALF) C0[(size_t)row * HALF + col] = f2b(acc[cf][j]);
            else            C1[(size_t)row * (NT - HALF) + (col - HALF)] = f2b(acc[cf][j]);
        }
    }
}

// ---------------------------------------------------------------------------
#define ROWB ((N_NODES + 31) / 32)          // 313
#define G1_BLOCKS (2 * ROWB)                // 626 (NT=256 / BN=128)
#define FILL_BLOCKS ((N_EDGES + 255) / 256) // 625

// SPLIT (was fat): pure layer-1 GEMM
__global__ __launch_bounds__(256) void gemm1_kernel(
    const float* __restrict__ x, const ushort* __restrict__ wc1,
    ushort* __restrict__ XL, ushort* __restrict__ XR) {
    gemm_body<float, 128, 128, IN_DIM, 256, HID>(blockIdx.x / ROWB, blockIdx.x % ROWB,
                                                 x, wc1, XL, XR, N_NODES);
}

// SPLIT (was fat): pure ELL fill
__global__ __launch_bounds__(256) void fill_kernel(
    const int* __restrict__ src, const int* __restrict__ dst,
    int* __restrict__ deg, int* __restrict__ bell) {
    int e = blockIdx.x * 256 + threadIdx.x;
    if (e < N_EDGES) {
        int d = dst[e];
        int pos = atomicAdd(&deg[d], 1);
        if (pos < CAP) bell[d * CAP + pos] = src[e];
    }
}

// Layer-2 GEMM: K=BK=128 -> single staging iteration
__global__ __launch_bounds__(256) void gemm2_kernel(
    const ushort* __restrict__ hb, const ushort* __restrict__ wc2,
    ushort* __restrict__ HL, ushort* __restrict__ HR) {
    gemm_body<ushort, 64, 128, HID, 128, OUT_DIM>(blockIdx.x / ROWB, blockIdx.x % ROWB,
                                                  hb, wc2, HL, HR, N_NODES);
}

// ---------------------------------------------------------------------------
__global__ __launch_bounds__(256) void gather1(
    const ushort* __restrict__ V, const ushort* __restrict__ xr,
    const float* __restrict__ b, const int* __restrict__ deg,
    const int* __restrict__ bell, ushort* __restrict__ out) {
    int wave = threadIdx.x >> 6;
    int lane = threadIdx.x & 63;
    int n = blockIdx.x * 4 + wave;
    if (n >= N_NODES) return;

    int d = min(deg[n], CAP);
    const int* lst = bell + (size_t)n * CAP;

    float a0 = 0.f, a1 = 0.f;
    int i = 0;
    for (; i + 4 <= d; i += 4) {
        int s0 = lst[i], s1 = lst[i + 1], s2 = lst[i + 2], s3 = lst[i + 3];
        uint u0 = *(const uint*)(V + (size_t)s0 * 128 + lane * 2);
        uint u1 = *(const uint*)(V + (size_t)s1 * 128 + lane * 2);
        uint u2 = *(const uint*)(V + (size_t)s2 * 128 + lane * 2);
        uint u3 = *(const uint*)(V + (size_t)s3 * 128 + lane * 2);
        a0 += blo(u0) + blo(u1) + blo(u2) + blo(u3);
        a1 += bhi(u0) + bhi(u1) + bhi(u2) + bhi(u3);
    }
    for (; i < d; ++i) {
        uint u = *(const uint*)(V + (size_t)lst[i] * 128 + lane * 2);
        a0 += blo(u); a1 += bhi(u);
    }

    float inv = (d > 0) ? (1.0f / (float)d) : 0.0f;
    uint ux = *(const uint*)(xr + (size_t)n * 128 + lane * 2);
    float v0 = fmaxf(a0 * inv + blo(ux) + b[lane * 2], 0.f);
    float v1 = fmaxf(a1 * inv + bhi(ux) + b[lane * 2 + 1], 0.f);
    *(uint*)(out + (size_t)n * 128 + lane * 2) = pack2(v0, v1);
}

__global__ __launch_bounds__(256) void gather2(
    const ushort* __restrict__ V, const ushort* __restrict__ xr,
    const float* __restrict__ b, const int* __restrict__ deg,
    const int* __restrict__ bell, float* __restrict__ out) {
    int wave = threadIdx.x >> 6;
    int lane = threadIdx.x & 63;
    int n = blockIdx.x * 4 + wave;
    if (n >= N_NODES) return;

    int d = min(deg[n], CAP);
    const int* lst = bell + (size_t)n * CAP;

    float a0 = 0.f;
    int i = 0;
    for (; i + 4 <= d; i += 4) {
        int s0 = lst[i], s1 = lst[i + 1], s2 = lst[i + 2], s3 = lst[i + 3];
        a0 += blo((uint)V[(size_t)s0 * 64 + lane]) + blo((uint)V[(size_t)s1 * 64 + lane])
            + blo((uint)V[(size_t)s2 * 64 + lane]) + blo((uint)V[(size_t)s3 * 64 + lane]);
    }
    for (; i < d; ++i) a0 += blo((uint)V[(size_t)lst[i] * 64 + lane]);

    float inv = (d > 0) ? (1.0f / (float)d) : 0.0f;
    out[(size_t)n * 64 + lane] = a0 * inv + blo((uint)xr[(size_t)n * 64 + lane]) + b[lane];
}

// ---------------------------------------------------------------------------
// R16: fat split into gemm1 + fill (interference/fill isolation).
// ---------------------------------------------------------------------------
extern "C" void kernel_launch(void* const* d_in, const int* in_sizes, int n_in,
                              void* d_out, int out_size, void* d_ws, size_t ws_size,
                              hipStream_t stream) {
    const float* x   = (const float*)d_in[0];
    const int*   ei  = (const int*)d_in[1];
    const int*   src = ei;
    const int*   dst = ei + N_EDGES;
    const float* W1l = (const float*)d_in[2];
    const float* W1r = (const float*)d_in[3];
    const float* b1  = (const float*)d_in[4];
    const float* W2l = (const float*)d_in[5];
    const float* W2r = (const float*)d_in[6];
    const float* b2  = (const float*)d_in[7];
    float*       out = (float*)d_out;

    int* deg  = (int*)d_ws;                                 // N
    int* bell = deg + N_NODES;                              // N*CAP
    ushort* wc1 = (ushort*)(bell + (size_t)N_NODES * CAP);  // 2*128*512 bf16
    ushort* wc2 = wc1 + (size_t)2 * HID * IN_DIM;           // 2*64*128 bf16
    ushort* XL  = wc2 + (size_t)2 * OUT_DIM * HID;          // N*128 bf16
    ushort* XR  = XL + (size_t)N_NODES * HID;               // N*128 bf16
    ushort* hb  = XR + (size_t)N_NODES * HID;               // N*128 bf16
    ushort* HL  = hb + (size_t)N_NODES * HID;               // N*64 bf16
    ushort* HR  = HL + (size_t)N_NODES * OUT_DIM;           // N*64 bf16

    prep<<<(PREP_TOT + 255) / 256, 256, 0, stream>>>(deg, W1l, W1r, W2l, W2r, wc1, wc2);

    gemm1_kernel<<<G1_BLOCKS, 256, 0, stream>>>(x, wc1, XL, XR);

    fill_kernel<<<FILL_BLOCKS, 256, 0, stream>>>(src, dst, deg, bell);

    gather1<<<(N_NODES + 3) / 4, 256, 0, stream>>>(XL, XR, b1, deg, bell, hb);

    gemm2_kernel<<<2 * ROWB, 256, 0, stream>>>(hb, wc2, HL, HR);

    gather2<<<(N_NODES + 3) / 4, 256, 0, stream>>>(HL, HR, b2, deg, bell, out);
}